// Round 15
// baseline (138.818 us; speedup 1.0000x reference)
//
#include <hip/hip_runtime.h>
#include <cstdint>
#include <cstddef>

// Problem constants
#define BB 8
#define TT 1024
#define CC 512
#define HH 8
#define DD 64
#define MM (BB*TT)     // 8192 rows

typedef short s16x4 __attribute__((ext_vector_type(4)));
typedef _Float16 f16x8 __attribute__((ext_vector_type(8)));
typedef float f32x4  __attribute__((ext_vector_type(4)));
typedef unsigned u32x4 __attribute__((ext_vector_type(4)));

__device__ __forceinline__ short f2hs(float f) {
  _Float16 h = (_Float16)f;
  return __builtin_bit_cast(short, h);
}
__device__ __forceinline__ unsigned pkh(float a, float b) {
  return __builtin_bit_cast(unsigned, __builtin_amdgcn_cvt_pkrtz(a, b));
}

__device__ __forceinline__ f32x4 mfma16h(f16x8 a, f16x8 b, f32x4 c) {
  return __builtin_amdgcn_mfma_f32_16x16x32_f16(a, b, c, 0, 0, 0);
}

__device__ __forceinline__ void gload_lds16(const void* g, void* l) {
  __builtin_amdgcn_global_load_lds(
      (const __attribute__((address_space(1))) unsigned int*)g,
      (__attribute__((address_space(3))) unsigned int*)l, 16, 0, 0);
}

// ---------------------------------------------------------------------------
// Kernel 1: fp16 prep + maskAdd (vectorized x4) + grid-barrier state zeroing.
// ---------------------------------------------------------------------------
__global__ void prep_kernel(const float* __restrict__ x,
                            const float* __restrict__ mask,
                            const float* __restrict__ Wq,
                            const float* __restrict__ Wk,
                            const float* __restrict__ Wv,
                            const float* __restrict__ Wp,
                            short* __restrict__ Xh,
                            short* __restrict__ Wqkv,
                            short* __restrict__ Wpc,
                            float* __restrict__ maskAdd,
                            unsigned* __restrict__ bar) {
  if (blockIdx.x == 0 && threadIdx.x == 0) { bar[0] = 0u; bar[1] = 0u; }
  const int NXv = MM * CC / 4;     // 1,048,576 float4 groups
  const int NWv = CC * CC / 4;     // 65,536 per weight
  const int NM = BB * TT;          // 8192
  int stride = gridDim.x * blockDim.x;
  for (int i = blockIdx.x * blockDim.x + threadIdx.x; i < NXv + 4 * NWv + NM; i += stride) {
    if (i < NXv) {
      int e = i * 4;
      float4 v = *(const float4*)(x + e);
      s16x4 h = {f2hs(v.x), f2hs(v.y), f2hs(v.z), f2hs(v.w)};
      *(s16x4*)(Xh + e) = h;
    } else if (i < NXv + 4 * NWv) {
      int wi = i - NXv;
      int wsel = wi >> 16;                 // 0=Wq 1=Wk 2=Wv 3=Wp
      int idx = wi & 65535;
      int r = idx >> 7, c = (idx & 127) << 2;
      const float* W = (wsel == 0) ? Wq : (wsel == 1) ? Wk : (wsel == 2) ? Wv : Wp;
      float4 v = *(const float4*)(W + (size_t)r * CC + c);
      s16x4 h = {f2hs(v.x), f2hs(v.y), f2hs(v.z), f2hs(v.w)};
      short* dst = (wsel < 3) ? (Wqkv + (size_t)(wsel * 512 + r) * CC + c)
                              : (Wpc + (size_t)r * CC + c);
      *(s16x4*)dst = h;
    } else {
      int mi = i - NXv - 4 * NWv;
      maskAdd[mi] = (mask[mi] == 0.f) ? -1e30f : 0.f;
    }
  }
}

// ---------------------------------------------------------------------------
// QKV GEMM v2: BM=128, BN=96, 8 waves (4M x 2N), 2-phase/K-tile, LDS 57344
// (2 x (16K A + 12K B)) -> GUARANTEED 2 blocks/CU (114688 << 160K).
// Grid (64,16) = 1024 blocks = exactly 2 dispatch rounds at 2/CU, no tail.
// Double-buffered A and B, gload_lds staging with XOR swizzle, setprio.
// Epilogue: scatter q (pre-scaled 1/8), k -> (B,H,T,64); v -> vt (B,H,64,T).
// ---------------------------------------------------------------------------
__global__ __launch_bounds__(512, 4) void qkv_kernel(
    const short* __restrict__ A, const short* __restrict__ Bw,
    const float* __restrict__ b0, const float* __restrict__ b1,
    const float* __restrict__ b2,
    short* __restrict__ qo, short* __restrict__ ko, short* __restrict__ vt) {
  constexpr int MR = 2, NR = 3;
  constexpr int ABYT = 16384;          // 128 rows x 128B
  constexpr int BBYT = 96 * 128;       // 12288
  constexpr int TILE = ABYT + BBYT;    // 28672
  constexpr int NT = 8;                // K=512 / 64
  __shared__ __align__(1024) char smem[2 * TILE];   // 57344

  const int tid = threadIdx.x;
  const int lane = tid & 63;
  const int w = tid >> 6;              // 0..7
  const int wm = w >> 1, wn = w & 1;   // 4M x 2N
  const int l15 = lane & 15, lg = lane >> 4;
  const int lsw = (l15 & 7) << 4;
  const int sr8 = lane >> 3;
  const int scbsw = ((lane & 7) * 16) ^ (sr8 << 4);

  const int rowA = blockIdx.x * 128;
  const int rowB = blockIdx.y * 96;
  const char* Ab = (const char*)A + (size_t)(rowA + sr8) * 1024 + scbsw;
  const char* Bb = (const char*)Bw + (size_t)(rowB + sr8) * 1024 + scbsw;

  f32x4 acc[MR][NR] = {};

  auto STAGE_A = [&](char* dst, int kt) {
#pragma unroll
    for (int g = 0; g < 2; ++g) {
      int r0 = (w * 2 + g) * 8;
      gload_lds16(Ab + (size_t)r0 * 1024 + (size_t)kt * 128, dst + r0 * 128);
    }
  };
  auto STAGE_B = [&](char* dst, int kt) {
    int r0 = w * 8;
    gload_lds16(Bb + (size_t)r0 * 1024 + (size_t)kt * 128, dst + ABYT + r0 * 128);
    if (w < 4) {
      int r1 = (8 + w) * 8;
      gload_lds16(Bb + (size_t)r1 * 1024 + (size_t)kt * 128, dst + ABYT + r1 * 128);
    }
  };
  auto RDA = [&](const char* buf, int kk, f16x8* af) {
#pragma unroll
    for (int i = 0; i < MR; ++i) {
      int row = wm * 32 + i * 16 + l15;
      af[i] = *(const f16x8*)(buf + row * 128 + ((kk * 64 + lg * 16) ^ lsw));
    }
  };
  auto RDB = [&](const char* buf, int kk, f16x8* bfr) {
#pragma unroll
    for (int j = 0; j < NR; ++j) {
      int row = wn * 48 + j * 16 + l15;
      bfr[j] = *(const f16x8*)(buf + ABYT + row * 128 + ((kk * 64 + lg * 16) ^ lsw));
    }
  };

  STAGE_A(smem, 0);
  STAGE_B(smem, 0);
  asm volatile("s_waitcnt vmcnt(0)" ::: "memory");
  __builtin_amdgcn_s_barrier();

  for (int t = 0; t < NT; ++t) {
    char* bufp = smem + (t & 1) * TILE;
    char* bufn = smem + ((t + 1) & 1) * TILE;
    f16x8 af[MR], bfr[NR];

    // phase 0 (kk=0): reads + A-stage issue
    RDB(bufp, 0, bfr);
    RDA(bufp, 0, af);
    if (t + 1 < NT) STAGE_A(bufn, t + 1);
    __builtin_amdgcn_s_barrier();
    asm volatile("s_waitcnt lgkmcnt(0)" ::: "memory");
    __builtin_amdgcn_sched_barrier(0);
    __builtin_amdgcn_s_setprio(1);
#pragma unroll
    for (int i = 0; i < MR; ++i)
#pragma unroll
      for (int j = 0; j < NR; ++j)
        acc[i][j] = mfma16h(af[i], bfr[j], acc[i][j]);
    __builtin_amdgcn_s_setprio(0);

    // phase 1 (kk=1): reads + B-stage issue
    RDB(bufp, 1, bfr);
    RDA(bufp, 1, af);
    if (t + 1 < NT) STAGE_B(bufn, t + 1);
    __builtin_amdgcn_s_barrier();
    asm volatile("s_waitcnt lgkmcnt(0)" ::: "memory");
    __builtin_amdgcn_sched_barrier(0);
    __builtin_amdgcn_s_setprio(1);
#pragma unroll
    for (int i = 0; i < MR; ++i)
#pragma unroll
      for (int j = 0; j < NR; ++j)
        acc[i][j] = mfma16h(af[i], bfr[j], acc[i][j]);
    __builtin_amdgcn_s_setprio(0);

    // tile end: drain staged loads, release bufp
    asm volatile("s_waitcnt vmcnt(0)" ::: "memory");
    __builtin_amdgcn_s_barrier();
  }

  // epilogue: row = rowA + wm*32 + m*16 + lg*4 + j, col = rowB + wn*48 + n*16 + l15
#pragma unroll
  for (int m = 0; m < MR; ++m) {
    int rbase = rowA + wm * 32 + m * 16 + lg * 4;
#pragma unroll
    for (int n = 0; n < NR; ++n) {
      int col = rowB + wn * 48 + n * 16 + l15;
#pragma unroll
      for (int j = 0; j < 4; ++j) {
        float v = acc[m][n][j];
        int r = rbase + j;
        int b = r >> 10, t = r & 1023;
        int wsel = col >> 9, c = col & 511;
        int h = c >> 6, dd = c & 63;
        int bh = b * HH + h;
        if (wsel == 0) {
          qo[((size_t)bh * TT + t) * DD + dd] = f2hs((v + b0[c]) * 0.125f);
        } else if (wsel == 1) {
          ko[((size_t)bh * TT + t) * DD + dd] = f2hs(v + b1[c]);
        } else {
          vt[((size_t)bh * DD + dd) * TT + t] = f2hs(v + b2[c]);
        }
      }
    }
  }
}

// ---------------------------------------------------------------------------
// Fused attention + output projection with a device-scope grid barrier.
// 512 blocks x 512 thr, LDS 65536 -> 2 blocks/CU guaranteed (131072 < 160K),
// launch_bounds(512,4) caps VGPR at 128 -> all 512 blocks co-resident.
// Phase A (attn): 2 virtual 4-wave units per block (different bh, SAME qb ->
// barrier-aligned, zero idle). qb map: blk<256 -> qb=lin>>5 (0..7);
// blk>=256 -> 15-(lin>>5) (8..15); co-resident pair (i,i+256) sums to 15.
// Phase B (proj): BM=128 BN=64, grid (64,8)=512, 4-phase pipelined.
// ---------------------------------------------------------------------------
__global__ __launch_bounds__(512, 4) void attnproj_kernel(
    const short* __restrict__ q, const short* __restrict__ k,
    const short* __restrict__ vt, const float* __restrict__ maskAdd,
    short* __restrict__ Yh, const short* __restrict__ Wpc,
    const float* __restrict__ bp, float* __restrict__ out,
    unsigned* __restrict__ bar) {
  __shared__ __align__(1024) char smem[65536];

  const int blk = blockIdx.x;
  const int tid = threadIdx.x;

  // ============================ Phase A: attention ==========================
  {
    const int half = blk >> 8;
    const int lin = blk & 255;
    const int qb = half ? (15 - (lin >> 5)) : (lin >> 5);
    const int bhp = lin & 31;
    const int w8 = tid >> 6;           // 0..7
    const int u = w8 >> 2;             // virtual unit 0/1
    const int w = w8 & 3;              // wave within unit
    const int bh = bhp * 2 + u;
    const int b = bh >> 3, h = bh & 7;
    const int lane = tid & 63;
    const int l15 = lane & 15, lg = lane >> 4;
    const int lsw = (l15 & 7) << 4;

    char* KsU = smem + u * 32768;      // Ks[2]: +0,+8192; Vs[2]: +16384,+24576

    const short* kbh = k + (size_t)bh * TT * DD;
    const short* vbh = vt + (size_t)bh * DD * TT;

    const int utid = tid & 255;
    const int sr32 = utid >> 3;        // 0..31
    const int scb = (utid & 7) * 16;

    auto STAGE = [&](int bs, int tile) {
#pragma unroll
      for (int g = 0; g < 2; ++g) {
        int row = g * 32 + sr32;
        int sw = (row & 7) << 4;
        gload_lds16((const char*)kbh + ((size_t)tile * 64 + row) * 128 + (scb ^ sw),
                    KsU + bs * 8192 + row * 128);
        gload_lds16((const char*)vbh + (size_t)row * 2048 + tile * 128 + (scb ^ sw),
                    KsU + 16384 + bs * 8192 + row * 128);
      }
    };

    const int qrow = qb * 64 + w * 16 + l15;
    const short* qptr = q + ((size_t)bh * TT + qrow) * DD;
    f16x8 qf0 = *(const f16x8*)(qptr + lg * 8);
    f16x8 qf1 = *(const f16x8*)(qptr + 32 + lg * 8);

    f32x4 yacc[4] = {};
    float mrun = -1e30f, lpart = 0.f;

    const int srcA = (((2 * lg) & 3) << 4) + l15;
    const int srcB = (((2 * lg + 1) & 3) << 4) + l15;
    const bool hiSel = (lg >= 2);

    STAGE(0, 0);
    __syncthreads();

    int buf = 0;
    for (int jt = 0; jt <= qb; ++jt) {
      if (jt < qb) STAGE(buf ^ 1, jt + 1);

      f32x4 sacc[4];
#pragma unroll
      for (int n = 0; n < 4; ++n)
        sacc[n] = *(const f32x4*)(maskAdd + (size_t)b * TT + jt * 64 + n * 16 + lg * 4);
      __builtin_amdgcn_s_setprio(1);
#pragma unroll
      for (int c = 0; c < 2; ++c) {
        f16x8 qc = (c == 0) ? qf0 : qf1;
#pragma unroll
        for (int n = 0; n < 4; ++n) {
          int krow = n * 16 + l15;
          const f16x8 kf = *(const f16x8*)(KsU + buf * 8192 + krow * 128 + ((c * 64 + lg * 16) ^ lsw));
          sacc[n] = mfma16h(kf, qc, sacc[n]);
        }
      }
      __builtin_amdgcn_s_setprio(0);
      if (jt == qb) {
        const int qloc8 = (w * 16 + l15) >> 3;
#pragma unroll
        for (int n = 0; n < 4; ++n)
#pragma unroll
          for (int jj = 0; jj < 4; ++jj) {
            int kloc = n * 16 + lg * 4 + jj;
            if ((kloc >> 3) > qloc8) sacc[n][jj] = -1e30f;
          }
      }
      float t0 = fmaxf(fmaxf(sacc[0][0], sacc[0][1]), fmaxf(sacc[0][2], sacc[0][3]));
      float t1 = fmaxf(fmaxf(sacc[1][0], sacc[1][1]), fmaxf(sacc[1][2], sacc[1][3]));
      float t2 = fmaxf(fmaxf(sacc[2][0], sacc[2][1]), fmaxf(sacc[2][2], sacc[2][3]));
      float t3 = fmaxf(fmaxf(sacc[3][0], sacc[3][1]), fmaxf(sacc[3][2], sacc[3][3]));
      float pmL = fmaxf(fmaxf(t0, t1), fmaxf(t2, t3));
      if (!__all(pmL <= mrun + 8.0f)) {
        float pm = fmaxf(pmL, __shfl_xor(pmL, 16));
        pm = fmaxf(pm, __shfl_xor(pm, 32));
        float mnew = fmaxf(mrun, pm);
        float alpha = __expf(mrun - mnew);
        mrun = mnew;
        lpart *= alpha;
        float ab[4];
#pragma unroll
        for (int jj = 0; jj < 4; ++jj) ab[jj] = __shfl(alpha, lg * 4 + jj);
#pragma unroll
        for (int dt = 0; dt < 4; ++dt)
#pragma unroll
          for (int jj = 0; jj < 4; ++jj) yacc[dt][jj] *= ab[jj];
      }
      unsigned pk2[4][2];
      float lps = 0.f;
#pragma unroll
      for (int n = 0; n < 4; ++n) {
        float p0 = __expf(sacc[n][0] - mrun);
        float p1 = __expf(sacc[n][1] - mrun);
        float p2 = __expf(sacc[n][2] - mrun);
        float p3 = __expf(sacc[n][3] - mrun);
        lps += (p0 + p1) + (p2 + p3);
        pk2[n][0] = pkh(p0, p1);
        pk2[n][1] = pkh(p2, p3);
      }
      lpart += lps;
      f16x8 pa[2];
#pragma unroll
      for (int c = 0; c < 2; ++c) {
        unsigned a0 = __shfl(pk2[2 * c][0], srcA);
        unsigned a1 = __shfl(pk2[2 * c][1], srcA);
        unsigned a2 = __shfl(pk2[2 * c][0], srcB);
        unsigned a3 = __shfl(pk2[2 * c][1], srcB);
        unsigned b0 = __shfl(pk2[2 * c + 1][0], srcA);
        unsigned b1 = __shfl(pk2[2 * c + 1][1], srcA);
        unsigned b2 = __shfl(pk2[2 * c + 1][0], srcB);
        unsigned b3 = __shfl(pk2[2 * c + 1][1], srcB);
        u32x4 tv = {hiSel ? b0 : a0, hiSel ? b1 : a1, hiSel ? b2 : a2, hiSel ? b3 : a3};
        pa[c] = __builtin_bit_cast(f16x8, tv);
      }
      __builtin_amdgcn_s_setprio(1);
#pragma unroll
      for (int c = 0; c < 2; ++c) {
#pragma unroll
        for (int dt = 0; dt < 4; ++dt) {
          int vrow = dt * 16 + l15;
          const f16x8 vf = *(const f16x8*)(KsU + 16384 + buf * 8192 + vrow * 128 + ((c * 64 + lg * 16) ^ lsw));
          yacc[dt] = mfma16h(pa[c], vf, yacc[dt]);
        }
      }
      __builtin_amdgcn_s_setprio(0);

      __syncthreads();
      buf ^= 1;
    }

    float lr = lpart;
    lr += __shfl_xor(lr, 16);
    lr += __shfl_xor(lr, 32);
    float lb[4];
#pragma unroll
    for (int jj = 0; jj < 4; ++jj) lb[jj] = 1.f / __shfl(lr, lg * 4 + jj);
#pragma unroll
    for (int dt = 0; dt < 4; ++dt) {
      int col = h * DD + dt * 16 + l15;
#pragma unroll
      for (int jj = 0; jj < 4; ++jj) {
        int row = b * TT + qb * 64 + w * 16 + lg * 4 + jj;
        float y = yacc[dt][jj] * lb[jj];
        Yh[(size_t)row * CC + col] = f2hs(y);
      }
    }
  }

  // ====================== device-scope grid barrier =========================
  __syncthreads();
  if (tid == 0) {
    __threadfence();                       // release: Yh visible device-wide
    if (atomicAdd(&bar[0], 1u) == 511u) {
      atomicAdd(&bar[1], 1u);
    } else {
      while (atomicAdd(&bar[1], 0u) == 0u) __builtin_amdgcn_s_sleep(8);
    }
    __threadfence();                       // acquire: invalidate stale caches
  }
  __syncthreads();

  // ======================= Phase B: proj GEMM (BN=64) =======================
  {
    constexpr int ABYT = 16384;            // 128 rows x 128B
    constexpr int TILE = 24576;            // + 64 x 128B
    constexpr int NT = 8;
    const int bx = blk & 63, by = blk >> 6;
    const int lane = tid & 63;
    const int w = tid >> 6;
    const int wm = w >> 2, wn = w & 3;
    const int l15 = lane & 15, lg = lane >> 4;
    const int lsw = (l15 & 7) << 4;
    const int sr8 = lane >> 3;
    const int scbsw = ((lane & 7) * 16) ^ (sr8 << 4);

    const int rowA = bx * 128;
    const int rowB = by * 64;
    const char* Ab = (const char*)Yh + (size_t)(rowA + sr8) * 1024 + scbsw;
    const char* Bb = (const char*)Wpc + (size_t)(rowB + sr8) * 1024 + scbsw;

    f32x4 acc[4] = {};

    auto STAGE_A = [&](char* dst, int kt) {
#pragma unroll
      for (int g = 0; g < 2; ++g) {
        int r0 = (w * 2 + g) * 8;
        gload_lds16(Ab + (size_t)r0 * 1024 + (size_t)kt * 128, dst + r0 * 128);
      }
    };
    auto STAGE_B = [&](char* dst, int kt) {
      int r0 = w * 8;
      gload_lds16(Bb + (size_t)r0 * 1024 + (size_t)kt * 128, dst + ABYT + r0 * 128);
    };
    auto RDA2 = [&](const char* buf, int mh, int kk, f16x8* af) {
#pragma unroll
      for (int i = 0; i < 2; ++i) {
        int row = wm * 64 + (mh * 2 + i) * 16 + l15;
        af[i] = *(const f16x8*)(buf + row * 128 + ((kk * 64 + lg * 16) ^ lsw));
      }
    };
    auto RDB1 = [&](const char* buf, int kk) {
      int row = wn * 16 + l15;
      return *(const f16x8*)(buf + ABYT + row * 128 + ((kk * 64 + lg * 16) ^ lsw));
    };

    STAGE_A(smem, 0);
    STAGE_B(smem, 0);
    asm volatile("s_waitcnt vmcnt(0)" ::: "memory");
    __builtin_amdgcn_s_barrier();

    for (int t = 0; t < NT; ++t) {
      char* bufp = smem + (t & 1) * TILE;
      char* bufn = smem + ((t + 1) & 1) * TILE;
      f16x8 af[2], bfr;

#define PJ(MH)                                                                \
  __builtin_amdgcn_s_barrier();                                               \
  asm volatile("s_waitcnt lgkmcnt(0)" ::: "memory");                          \
  __builtin_amdgcn_sched_barrier(0);                                          \
  __builtin_amdgcn_s_setprio(1);                                              \
  _Pragma("unroll")                                                           \
  for (int i = 0; i < 2; ++i)                                                 \
    acc[(MH) * 2 + i] = mfma16h(af[i], bfr, acc[(MH) * 2 + i]);               \
  __builtin_amdgcn_s_setprio(0);

      bfr = RDB1(bufp, 0);
      RDA2(bufp, 0, 0, af);
      if (t + 1 < NT) STAGE_A(bufn, t + 1);
      PJ(0)
      RDA2(bufp, 1, 0, af);
      if (t + 1 < NT) STAGE_B(bufn, t + 1);
      PJ(1)
      bfr = RDB1(bufp, 1);
      RDA2(bufp, 1, 1, af);
      PJ(1)
      RDA2(bufp, 0, 1, af);
      PJ(0)
#undef PJ
      asm volatile("s_waitcnt vmcnt(0)" ::: "memory");
      __builtin_amdgcn_s_barrier();
    }

#pragma unroll
    for (int m = 0; m < 4; ++m) {
      int rbase = rowA + wm * 64 + m * 16 + lg * 4;
      int col = rowB + wn * 16 + l15;
#pragma unroll
      for (int j = 0; j < 4; ++j) {
        out[(size_t)(rbase + j) * CC + col] = acc[m][j] + bp[col];
      }
    }
  }
}

// ---------------------------------------------------------------------------
extern "C" void kernel_launch(void* const* d_in, const int* in_sizes, int n_in,
                              void* d_out, int out_size, void* d_ws, size_t ws_size,
                              hipStream_t stream) {
  const float* x    = (const float*)d_in[0];
  const float* mask = (const float*)d_in[1];
  const float* Wq   = (const float*)d_in[2];
  const float* bq   = (const float*)d_in[3];
  const float* Wk   = (const float*)d_in[4];
  const float* bk   = (const float*)d_in[5];
  const float* Wv   = (const float*)d_in[6];
  const float* bv   = (const float*)d_in[7];
  const float* Wp   = (const float*)d_in[8];
  const float* bp   = (const float*)d_in[9];
  float* out = (float*)d_out;

  char* ws = (char*)d_ws;
  short* Xh   = (short*)(ws);                          // 8 MB
  short* Wqkv = (short*)(ws + (size_t)8 * 1048576);    // 1.5 MB
  short* Wpc  = (short*)(ws + (size_t)10 * 1048576);   // 0.5 MB
  short* qo   = (short*)(ws + (size_t)11 * 1048576);   // 8 MB
  short* ko   = (short*)(ws + (size_t)19 * 1048576);   // 8 MB
  short* vt   = (short*)(ws + (size_t)27 * 1048576);   // 8 MB
  short* Yh   = (short*)(ws + (size_t)35 * 1048576);   // 8 MB
  float* maskAdd = (float*)(ws + (size_t)43 * 1048576); // 32 KB
  unsigned* bar  = (unsigned*)(ws + (size_t)44 * 1048576); // 8 B

  prep_kernel<<<2048, 256, 0, stream>>>(x, mask, Wq, Wk, Wv, Wp, Xh, Wqkv, Wpc,
                                        maskAdd, bar);

  // QKV: BM=128, BN=96 -> grid (64,16) = 1024 blocks, guaranteed 2/CU
  qkv_kernel<<<dim3(64, 16), 512, 0, stream>>>(
      Xh, Wqkv, bq, bk, bv, qo, ko, vt);

  // fused attn (2 units/block, same-qb pairing) + grid barrier + proj
  attnproj_kernel<<<dim3(512), 512, 0, stream>>>(
      qo, ko, vt, maskAdd, Yh, Wpc, bp, out, bar);
}

// Round 16
// 72.890 us; speedup vs baseline: 1.9045x; 1.9045x over previous
//
#include <hip/hip_runtime.h>
#include <cstdint>
#include <cstddef>

// Problem constants
#define BB 8
#define TT 1024
#define CC 512
#define HH 8
#define DD 64
#define MM (BB*TT)     // 8192 rows

typedef short s16x4 __attribute__((ext_vector_type(4)));
typedef _Float16 f16x8 __attribute__((ext_vector_type(8)));
typedef float f32x4  __attribute__((ext_vector_type(4)));
typedef unsigned u32x4 __attribute__((ext_vector_type(4)));

__device__ __forceinline__ short f2hs(float f) {
  _Float16 h = (_Float16)f;
  return __builtin_bit_cast(short, h);
}
__device__ __forceinline__ unsigned pkh(float a, float b) {
  return __builtin_bit_cast(unsigned, __builtin_amdgcn_cvt_pkrtz(a, b));
}

__device__ __forceinline__ f32x4 mfma16h(f16x8 a, f16x8 b, f32x4 c) {
  return __builtin_amdgcn_mfma_f32_16x16x32_f16(a, b, c, 0, 0, 0);
}

__device__ __forceinline__ void gload_lds16(const void* g, void* l) {
  __builtin_amdgcn_global_load_lds(
      (const __attribute__((address_space(1))) unsigned int*)g,
      (__attribute__((address_space(3))) unsigned int*)l, 16, 0, 0);
}

// ---------------------------------------------------------------------------
// Kernel 1: fp16 prep + maskAdd (vectorized x4).  (R10 exact)
// ---------------------------------------------------------------------------
__global__ void prep_kernel(const float* __restrict__ x,
                            const float* __restrict__ mask,
                            const float* __restrict__ Wq,
                            const float* __restrict__ Wk,
                            const float* __restrict__ Wv,
                            const float* __restrict__ Wp,
                            short* __restrict__ Xh,
                            short* __restrict__ Wqkv,
                            short* __restrict__ Wpc,
                            float* __restrict__ maskAdd) {
  const int NXv = MM * CC / 4;     // 1,048,576 float4 groups
  const int NWv = CC * CC / 4;     // 65,536 per weight
  const int NM = BB * TT;          // 8192
  int stride = gridDim.x * blockDim.x;
  for (int i = blockIdx.x * blockDim.x + threadIdx.x; i < NXv + 4 * NWv + NM; i += stride) {
    if (i < NXv) {
      int e = i * 4;
      float4 v = *(const float4*)(x + e);
      s16x4 h = {f2hs(v.x), f2hs(v.y), f2hs(v.z), f2hs(v.w)};
      *(s16x4*)(Xh + e) = h;
    } else if (i < NXv + 4 * NWv) {
      int wi = i - NXv;
      int wsel = wi >> 16;                 // 0=Wq 1=Wk 2=Wv 3=Wp
      int idx = wi & 65535;
      int r = idx >> 7, c = (idx & 127) << 2;
      const float* W = (wsel == 0) ? Wq : (wsel == 1) ? Wk : (wsel == 2) ? Wv : Wp;
      float4 v = *(const float4*)(W + (size_t)r * CC + c);
      s16x4 h = {f2hs(v.x), f2hs(v.y), f2hs(v.z), f2hs(v.w)};
      short* dst = (wsel < 3) ? (Wqkv + (size_t)(wsel * 512 + r) * CC + c)
                              : (Wpc + (size_t)r * CC + c);
      *(s16x4*)dst = h;
    } else {
      int mi = i - NXv - 4 * NWv;
      maskAdd[mi] = (mask[mi] == 0.f) ? -1e30f : 0.f;
    }
  }
}

// ---------------------------------------------------------------------------
// 4-phase pipelined fp16 GEMM (R7/R10 structure, proven).
// EPI==0: scatter q (pre-scaled 1/8), k -> (B,H,T,64); v -> vt (B,H,64,T)
// EPI==1: out fp32 = acc + bias
// ---------------------------------------------------------------------------
template <int BN, int EPI>
__global__ __launch_bounds__(512, 4) void gemm_kernel(
    const short* __restrict__ A, const short* __restrict__ Bw,
    const float* __restrict__ b0, const float* __restrict__ b1,
    const float* __restrict__ b2,
    short* __restrict__ qo, short* __restrict__ ko, short* __restrict__ vt,
    float* __restrict__ outp) {
  constexpr int MR = 4;
  constexpr int NR = BN / 64;          // 3 (qkv) / 2 (proj)
  constexpr int ABYT = 128 * 128;
  constexpr int TILE = ABYT + BN * 128;
  constexpr int NT = 8;                // K=512 / 64
  constexpr int BL = BN / 64;
  __shared__ __align__(1024) char smem[2 * TILE];

  const int tid = threadIdx.x;
  const int lane = tid & 63;
  const int w = tid >> 6;
  const int wm = w >> 2, wn = w & 3;
  const int l15 = lane & 15, lg = lane >> 4;
  const int lsw = (l15 & 7) << 4;
  const int sr8 = lane >> 3;
  const int scbsw = ((lane & 7) * 16) ^ (sr8 << 4);

  const int rowA = blockIdx.x * 128;
  const int rowB = blockIdx.y * BN;
  const char* Ab = (const char*)A + (size_t)(rowA + sr8) * 1024 + scbsw;
  const char* Bb = (const char*)Bw + (size_t)(rowB + sr8) * 1024 + scbsw;

  f32x4 acc[MR][NR] = {};

  auto STAGE_A = [&](char* dst, int kt) {
#pragma unroll
    for (int g = 0; g < 2; ++g) {
      int r0 = (w * 2 + g) * 8;
      gload_lds16(Ab + (size_t)r0 * 1024 + (size_t)kt * 128, dst + r0 * 128);
    }
  };
  auto STAGE_B = [&](char* dst, int kt) {
#pragma unroll
    for (int g = 0; g < BL; ++g) {
      int r0 = (w * BL + g) * 8;
      gload_lds16(Bb + (size_t)r0 * 1024 + (size_t)kt * 128, dst + ABYT + r0 * 128);
    }
  };
  auto RDA2 = [&](const char* buf, int mh, int kk, f16x8* af) {
#pragma unroll
    for (int i = 0; i < 2; ++i) {
      int row = wm * 64 + (mh * 2 + i) * 16 + l15;
      af[i] = *(const f16x8*)(buf + row * 128 + ((kk * 64 + lg * 16) ^ lsw));
    }
  };
  auto RDBk = [&](const char* buf, int kk, f16x8* bfr) {
#pragma unroll
    for (int j = 0; j < NR; ++j) {
      int row = wn * (BN / 4) + j * 16 + l15;
      bfr[j] = *(const f16x8*)(buf + ABYT + row * 128 + ((kk * 64 + lg * 16) ^ lsw));
    }
  };

  STAGE_A(smem, 0);
  STAGE_B(smem, 0);
  asm volatile("s_waitcnt vmcnt(0)" ::: "memory");
  __builtin_amdgcn_s_barrier();

  for (int t = 0; t < NT; ++t) {
    char* bufp = smem + (t & 1) * TILE;
    char* bufn = smem + ((t + 1) & 1) * TILE;
    f16x8 af[2], bfr[NR];

#define PH(MH)                                                                \
  __builtin_amdgcn_s_barrier();                                               \
  asm volatile("s_waitcnt lgkmcnt(0)" ::: "memory");                          \
  __builtin_amdgcn_sched_barrier(0);                                          \
  __builtin_amdgcn_s_setprio(1);                                              \
  _Pragma("unroll")                                                           \
  for (int i = 0; i < 2; ++i)                                                 \
    _Pragma("unroll")                                                         \
    for (int j = 0; j < NR; ++j)                                              \
      acc[(MH) * 2 + i][j] = mfma16h(af[i], bfr[j], acc[(MH) * 2 + i][j]);    \
  __builtin_amdgcn_s_setprio(0);

    RDBk(bufp, 0, bfr);
    RDA2(bufp, 0, 0, af);
    if (t + 1 < NT) STAGE_A(bufn, t + 1);
    PH(0)
    RDA2(bufp, 1, 0, af);
    if (t + 1 < NT) STAGE_B(bufn, t + 1);
    PH(1)
    RDBk(bufp, 1, bfr);
    RDA2(bufp, 1, 1, af);
    PH(1)
    RDA2(bufp, 0, 1, af);
    PH(0)
#undef PH
    asm volatile("s_waitcnt vmcnt(0)" ::: "memory");
    __builtin_amdgcn_s_barrier();
  }

#pragma unroll
  for (int m = 0; m < MR; ++m) {
    int rbase = rowA + wm * 64 + m * 16 + lg * 4;
#pragma unroll
    for (int n = 0; n < NR; ++n) {
      int col = rowB + wn * (BN / 4) + n * 16 + l15;
#pragma unroll
      for (int j = 0; j < 4; ++j) {
        float v = acc[m][n][j];
        int r = rbase + j;
        if constexpr (EPI == 0) {
          int b = r >> 10, t = r & 1023;
          int wsel = col >> 9, c = col & 511;
          int h = c >> 6, dd = c & 63;
          int bh = b * HH + h;
          if (wsel == 0) {
            qo[((size_t)bh * TT + t) * DD + dd] = f2hs((v + b0[c]) * 0.125f);
          } else if (wsel == 1) {
            ko[((size_t)bh * TT + t) * DD + dd] = f2hs(v + b1[c]);
          } else {
            vt[((size_t)bh * DD + dd) * TT + t] = f2hs(v + b2[c]);
          }
        } else {
          outp[(size_t)r * CC + col] = v + b0[col];
        }
      }
    }
  }
}

// ---------------------------------------------------------------------------
// Flash attention v7 (fp16) — R10 exact (proven 73.3 baseline).
// Grid: 1024 blocks x 256 thr (4 waves); one (bh, qb) per block; 4 blocks/CU.
// Co-residency map gives each CU same-bh blocks with balanced qb sets.
// ---------------------------------------------------------------------------
__global__ __launch_bounds__(256, 4) void attn_kernel(
    const short* __restrict__ q, const short* __restrict__ k,
    const short* __restrict__ vt, const float* __restrict__ maskAdd,
    short* __restrict__ Yh) {
  const int blk = blockIdx.x;
  const int k4 = blk >> 8;             // 0..3 (co-residency round)
  const int r = blk & 255;
  const int bh = r >> 2;
  const int j4 = r & 3;
  const int qb = (k4 & 1) ? ((k4 & 2) ? (4 + j4) : j4)
                          : ((k4 & 2) ? (11 - j4) : (15 - j4));
  const int b = bh >> 3, h = bh & 7;
  const int tid = threadIdx.x;
  const int lane = tid & 63;
  const int w = tid >> 6;              // 0..3, owns q-rows w*16..w*16+15
  const int l15 = lane & 15, lg = lane >> 4;
  const int lsw = (l15 & 7) << 4;

  __shared__ short Ks[2][64 * 64];     // 16 KB
  __shared__ short Vs[2][64 * 64];     // 16 KB

  const short* kbh = k + (size_t)bh * TT * DD;
  const short* vbh = vt + (size_t)bh * DD * TT;

  const int sr32 = tid >> 3;           // 0..31
  const int scb = (tid & 7) * 16;

  auto STAGE = [&](int bs, int tile) {
#pragma unroll
    for (int g = 0; g < 2; ++g) {
      int row = g * 32 + sr32;
      int sw = (row & 7) << 4;
      gload_lds16((const char*)kbh + ((size_t)tile * 64 + row) * 128 + (scb ^ sw),
                  (char*)&Ks[bs][0] + row * 128);
      gload_lds16((const char*)vbh + (size_t)row * 2048 + tile * 128 + (scb ^ sw),
                  (char*)&Vs[bs][0] + row * 128);
    }
  };

  const int qrow = qb * 64 + w * 16 + l15;
  const short* qptr = q + ((size_t)bh * TT + qrow) * DD;
  f16x8 qf0 = *(const f16x8*)(qptr + lg * 8);
  f16x8 qf1 = *(const f16x8*)(qptr + 32 + lg * 8);

  f32x4 yacc[4] = {};
  float mrun = -1e30f, lpart = 0.f;

  const int srcA = (((2 * lg) & 3) << 4) + l15;
  const int srcB = (((2 * lg + 1) & 3) << 4) + l15;
  const bool hiSel = (lg >= 2);

  STAGE(0, 0);
  __syncthreads();

  int buf = 0;
  for (int jt = 0; jt <= qb; ++jt) {
    if (jt < qb) STAGE(buf ^ 1, jt + 1);

    f32x4 sacc[4];
#pragma unroll
    for (int n = 0; n < 4; ++n)
      sacc[n] = *(const f32x4*)(maskAdd + (size_t)b * TT + jt * 64 + n * 16 + lg * 4);
    __builtin_amdgcn_s_setprio(1);
#pragma unroll
    for (int c = 0; c < 2; ++c) {
      f16x8 qc = (c == 0) ? qf0 : qf1;
#pragma unroll
      for (int n = 0; n < 4; ++n) {
        int krow = n * 16 + l15;
        const f16x8 kf = *(const f16x8*)((const char*)&Ks[buf][0] + krow * 128 + ((c * 64 + lg * 16) ^ lsw));
        sacc[n] = mfma16h(kf, qc, sacc[n]);
      }
    }
    __builtin_amdgcn_s_setprio(0);
    if (jt == qb) {
      const int qloc8 = (w * 16 + l15) >> 3;
#pragma unroll
      for (int n = 0; n < 4; ++n)
#pragma unroll
        for (int jj = 0; jj < 4; ++jj) {
          int kloc = n * 16 + lg * 4 + jj;
          if ((kloc >> 3) > qloc8) sacc[n][jj] = -1e30f;
        }
    }
    float t0 = fmaxf(fmaxf(sacc[0][0], sacc[0][1]), fmaxf(sacc[0][2], sacc[0][3]));
    float t1 = fmaxf(fmaxf(sacc[1][0], sacc[1][1]), fmaxf(sacc[1][2], sacc[1][3]));
    float t2 = fmaxf(fmaxf(sacc[2][0], sacc[2][1]), fmaxf(sacc[2][2], sacc[2][3]));
    float t3 = fmaxf(fmaxf(sacc[3][0], sacc[3][1]), fmaxf(sacc[3][2], sacc[3][3]));
    float pmL = fmaxf(fmaxf(t0, t1), fmaxf(t2, t3));
    if (!__all(pmL <= mrun + 8.0f)) {
      float pm = fmaxf(pmL, __shfl_xor(pmL, 16));
      pm = fmaxf(pm, __shfl_xor(pm, 32));
      float mnew = fmaxf(mrun, pm);
      float alpha = __expf(mrun - mnew);
      mrun = mnew;
      lpart *= alpha;
      float ab[4];
#pragma unroll
      for (int jj = 0; jj < 4; ++jj) ab[jj] = __shfl(alpha, lg * 4 + jj);
#pragma unroll
      for (int dt = 0; dt < 4; ++dt)
#pragma unroll
        for (int jj = 0; jj < 4; ++jj) yacc[dt][jj] *= ab[jj];
    }
    unsigned pk2[4][2];
    float lps = 0.f;
#pragma unroll
    for (int n = 0; n < 4; ++n) {
      float p0 = __expf(sacc[n][0] - mrun);
      float p1 = __expf(sacc[n][1] - mrun);
      float p2 = __expf(sacc[n][2] - mrun);
      float p3 = __expf(sacc[n][3] - mrun);
      lps += (p0 + p1) + (p2 + p3);
      pk2[n][0] = pkh(p0, p1);
      pk2[n][1] = pkh(p2, p3);
    }
    lpart += lps;
    f16x8 pa[2];
#pragma unroll
    for (int c = 0; c < 2; ++c) {
      unsigned a0 = __shfl(pk2[2 * c][0], srcA);
      unsigned a1 = __shfl(pk2[2 * c][1], srcA);
      unsigned a2 = __shfl(pk2[2 * c][0], srcB);
      unsigned a3 = __shfl(pk2[2 * c][1], srcB);
      unsigned b0 = __shfl(pk2[2 * c + 1][0], srcA);
      unsigned b1 = __shfl(pk2[2 * c + 1][1], srcA);
      unsigned b2 = __shfl(pk2[2 * c + 1][0], srcB);
      unsigned b3 = __shfl(pk2[2 * c + 1][1], srcB);
      u32x4 tv = {hiSel ? b0 : a0, hiSel ? b1 : a1, hiSel ? b2 : a2, hiSel ? b3 : a3};
      pa[c] = __builtin_bit_cast(f16x8, tv);
    }
    __builtin_amdgcn_s_setprio(1);
#pragma unroll
    for (int c = 0; c < 2; ++c) {
#pragma unroll
      for (int dt = 0; dt < 4; ++dt) {
        int vrow = dt * 16 + l15;
        const f16x8 vf = *(const f16x8*)((const char*)&Vs[buf][0] + vrow * 128 + ((c * 64 + lg * 16) ^ lsw));
        yacc[dt] = mfma16h(pa[c], vf, yacc[dt]);
      }
    }
    __builtin_amdgcn_s_setprio(0);

    __syncthreads();
    buf ^= 1;
  }

  float lr = lpart;
  lr += __shfl_xor(lr, 16);
  lr += __shfl_xor(lr, 32);
  float lb[4];
#pragma unroll
  for (int jj = 0; jj < 4; ++jj) lb[jj] = 1.f / __shfl(lr, lg * 4 + jj);
#pragma unroll
  for (int dt = 0; dt < 4; ++dt) {
    int col = h * DD + dt * 16 + l15;
#pragma unroll
    for (int jj = 0; jj < 4; ++jj) {
      int row = b * TT + qb * 64 + w * 16 + lg * 4 + jj;
      float y = yacc[dt][jj] * lb[jj];
      Yh[(size_t)row * CC + col] = f2hs(y);
    }
  }
}

// ---------------------------------------------------------------------------
extern "C" void kernel_launch(void* const* d_in, const int* in_sizes, int n_in,
                              void* d_out, int out_size, void* d_ws, size_t ws_size,
                              hipStream_t stream) {
  const float* x    = (const float*)d_in[0];
  const float* mask = (const float*)d_in[1];
  const float* Wq   = (const float*)d_in[2];
  const float* bq   = (const float*)d_in[3];
  const float* Wk   = (const float*)d_in[4];
  const float* bk   = (const float*)d_in[5];
  const float* Wv   = (const float*)d_in[6];
  const float* bv   = (const float*)d_in[7];
  const float* Wp   = (const float*)d_in[8];
  const float* bp   = (const float*)d_in[9];
  float* out = (float*)d_out;

  char* ws = (char*)d_ws;
  short* Xh   = (short*)(ws);                          // 8 MB
  short* Wqkv = (short*)(ws + (size_t)8 * 1048576);    // 1.5 MB
  short* Wpc  = (short*)(ws + (size_t)10 * 1048576);   // 0.5 MB
  short* qo   = (short*)(ws + (size_t)11 * 1048576);   // 8 MB
  short* ko   = (short*)(ws + (size_t)19 * 1048576);   // 8 MB
  short* vt   = (short*)(ws + (size_t)27 * 1048576);   // 8 MB
  short* Yh   = (short*)(ws + (size_t)35 * 1048576);   // 8 MB
  float* maskAdd = (float*)(ws + (size_t)43 * 1048576); // 32 KB

  prep_kernel<<<2048, 256, 0, stream>>>(x, mask, Wq, Wk, Wv, Wp, Xh, Wqkv, Wpc, maskAdd);

  // QKV: BN=192, grid (64,8) = 512 blocks = 2/CU
  gemm_kernel<192, 0><<<dim3(64, 8), 512, 0, stream>>>(
      Xh, Wqkv, bq, bk, bv, qo, ko, vt, nullptr);

  // attn: 1024 blocks x 256 thr, 4 blocks/CU, balanced qb co-residency
  attn_kernel<<<dim3(1024), 256, 0, stream>>>(qo, ko, vt, maskAdd, Yh);

  // proj: BN=128, grid (64,4) = 256 blocks
  gemm_kernel<128, 1><<<dim3(64, 4), 512, 0, stream>>>(
      Yh, Wpc, bp, nullptr, nullptr, nullptr, nullptr, nullptr, out);
}